// Round 13
// baseline (40.623 us; speedup 1.0000x reference)
//
#include <hip/hip_runtime.h>

#define N_IN   4096
#define N_OUT  4082      // 4096 - 15 + 1
#define KS     15
#define TM     128       // output rows per block (2 chunks x 64)
#define TN     128       // output cols per block
#define CH     64        // output rows per chunk (4 row-groups x 16)
#define PR     142       // patch rows staged (TM + KS - 1)
#define PC     144       // patch cols staged (TN + 16)
#define PCB    (PC * 2)  // patch row pitch in bytes = 288
#define C4R    36        // float4 chunks per patch row (PC/4)
#define PITEMS (78 * C4R)          // prologue items (rows [0,78)) = 2808
#define CITEMS (CH * C4R)          // chunk-0 staging items (rows [78,142)) = 2304

// R13: occupancy restructure. R9-R12 plateaued ~36us with nothing saturated:
// grid 512 = 2 blocks/CU hard cap (16 waves/CU) was the latency-hiding limit.
// Now: grid 1024 (TN=128), LDS = patch only (142x144 bf16 = 40,896 B, no
// ring/RMOD, 2 barriers/block), B-table in GLOBAL d_ws (block-invariant,
// filled by pre-kernel; L1/L2-resident, 1KB coalesced per entry per wave).
// Wave = 16 rows x 64 cols keeps shared-window pairing: 5 A-reads + 2
// B-loads feed 8 MFMAs.
// REGISTER LESSON (R4/5/7/8/10): B never in regs wholesale; target VGPR<=64
// (m69: waves/CU halves past 64). Spill gauge: WRITE_SIZE-66.6MB ~ 0.
// Bank: pitch 144 bf16 = 72 words == 8 mod 32 -> verified conflict-free
// b128 pattern (R6/R9/R12: 0 conflicts).

typedef __attribute__((ext_vector_type(8))) short bf16x8;
typedef __attribute__((ext_vector_type(4))) float f32x4;

__device__ inline unsigned short f2bf(float f) {   // round-to-nearest-even
    unsigned u = __builtin_bit_cast(unsigned, f);
    u += 0x7FFFu + ((u >> 16) & 1u);
    return (unsigned short)(u >> 16);
}
__device__ inline ushort4 f2bf4(float4 v) {
    ushort4 b; b.x = f2bf(v.x); b.y = f2bf(v.y); b.z = f2bf(v.z); b.w = f2bf(v.w);
    return b;
}

// load one staging item (patch row = base + it/C4R) into v, zero-padded
#define ISSUE_ITEM(base, it, v) {                                         \
    const int _row = (base) + (it) / C4R;                                 \
    const int _c4  = (it) % C4R;                                          \
    const int _gr  = r0 + _row;                                           \
    const int _gc  = c0 + _c4 * 4;                                        \
    if (_gr < N_IN && _gc < N_IN)                                         \
        v = *reinterpret_cast<const float4*>(&x[_gr * N_IN + _gc]);       \
}
// convert + write item into the patch buffer
#define COMMIT_ITEM(base, it, v) {                                        \
    const int _row = (base) + (it) / C4R;                                 \
    const int _c4  = (it) % C4R;                                          \
    *reinterpret_cast<ushort4*>(&xs[_row * PC + _c4 * 4]) = f2bf4(v);     \
}

#define MF(a, b, c) __builtin_amdgcn_mfma_f32_16x16x32_bf16((a), (b), (c), 0, 0, 0)

// ---- pre-kernel: build the 16-entry B table in global ws ----
// entry idx = P*2+h: B[k=16p'+q'][n=m] = wpad[2P+p'][q' + 16h - m]
__global__ __launch_bounds__(64) void btab_fill_kernel(
    const float* __restrict__ w, unsigned short* __restrict__ bt)
{
    const int idx  = blockIdx.x;          // 0..15
    const int lane = threadIdx.x;         // 0..63
    const int P  = idx >> 1, h = idx & 1;
    const int m  = lane & 15;
    const int g  = lane >> 4;
    const int gp = g >> 1, g1 = g & 1;
    bf16x8 f;
    #pragma unroll
    for (int e = 0; e < 8; ++e) {
        const int prow = 2 * P + gp;
        const int col  = g1 * 8 + e + 16 * h - m;
        const float vv = (prow < KS && col >= 0 && col < KS) ? w[prow * KS + col] : 0.f;
        f[e] = (short)f2bf(vv);
    }
    *reinterpret_cast<bf16x8*>(&bt[idx * 512 + lane * 8]) = f;
}

__global__ __launch_bounds__(512, 4) void Conv2DScratch_82025285419642_kernel(
    const float* __restrict__ x, const unsigned short* __restrict__ btab,
    const float* __restrict__ bias, float* __restrict__ out)
{
    __shared__ unsigned short xs[PR * PC];   // 40,896 B

    const int tid  = threadIdx.x;
    const int lane = tid & 63;
    const int wv   = tid >> 6;
    const int m    = lane & 15;           // A row within band / D col
    const int g    = lane >> 4;           // k-group / D row group
    const int gp   = g >> 1;              // p' within pair
    const int g1   = g & 1;               // q' high/low 8
    const int wr   = wv >> 1;             // row-group: rows [64c+16wr, +16)
    const int wc   = wv & 1;              // col-group: cols [64wc, 64wc+64)

    // bijective XCD-chunked block swizzle (1024 blocks, 8 XCDs, 128 each)
    const int bid = blockIdx.x;
    const int s   = ((bid & 7) << 7) | (bid >> 3);
    const int c0  = (s & 31) * TN;        // output col base
    const int r0  = (s >> 5) * TM;        // output row base

    // ---- prologue: stage patch rows [0,78) ----
    float4 p0 = make_float4(0.f,0.f,0.f,0.f), p1 = p0, p2 = p0,
           p3 = p0, p4 = p0, p5 = p0;
    ISSUE_ITEM(0, tid,        p0);
    ISSUE_ITEM(0, tid +  512, p1);
    ISSUE_ITEM(0, tid + 1024, p2);
    ISSUE_ITEM(0, tid + 1536, p3);
    ISSUE_ITEM(0, tid + 2048, p4);
    if (tid < PITEMS - 2560) ISSUE_ITEM(0, tid + 2560, p5);   // 248 tail
    const float b0 = bias[0];
    COMMIT_ITEM(0, tid,        p0);
    COMMIT_ITEM(0, tid +  512, p1);
    COMMIT_ITEM(0, tid + 1024, p2);
    COMMIT_ITEM(0, tid + 1536, p3);
    COMMIT_ITEM(0, tid + 2048, p4);
    if (tid < PITEMS - 2560) COMMIT_ITEM(0, tid + 2560, p5);
    __syncthreads();

    const unsigned char* xsb = (const unsigned char*)xs;
    const unsigned char* btb = (const unsigned char*)btab;
    const int cb0    = 128 * wc + 16 * g1;   // A-read byte offset within row
    const int lane16 = lane * 16;

    // one pair-step: 5 shared A-windows (LDS) + 2 B-frags (global, L1-hot)
    #define PPAIR(ROW) {                                                  \
        const unsigned char* _ab = xsb + (ROW) * PCB + cb0;               \
        const bf16x8 a0 = *reinterpret_cast<const bf16x8*>(_ab +   0);    \
        const bf16x8 a1 = *reinterpret_cast<const bf16x8*>(_ab +  32);    \
        const bf16x8 a2 = *reinterpret_cast<const bf16x8*>(_ab +  64);    \
        const bf16x8 a3 = *reinterpret_cast<const bf16x8*>(_ab +  96);    \
        const bf16x8 a4 = *reinterpret_cast<const bf16x8*>(_ab + 128);    \
        const bf16x8 bl = *reinterpret_cast<const bf16x8*>(                \
            btb + _Pb * 2048 + lane16);                                   \
        const bf16x8 bh = *reinterpret_cast<const bf16x8*>(                \
            btb + _Pb * 2048 + 1024 + lane16);                            \
        acc0 = MF(a0, bl, acc0); acc0 = MF(a1, bh, acc0);                 \
        acc1 = MF(a1, bl, acc1); acc1 = MF(a2, bh, acc1);                 \
        acc2 = MF(a2, bl, acc2); acc2 = MF(a3, bh, acc2);                 \
        acc3 = MF(a3, bl, acc3); acc3 = MF(a4, bh, acc3);                 \
    }

    #define DO_CHUNK(CBASE)                                               \
        f32x4 acc0 = {0.f,0.f,0.f,0.f}, acc1 = acc0, acc2 = acc0, acc3 = acc0; \
        const int rbg = (CBASE) + 16 * wr + m + gp;                       \
        const int rb7 = (CBASE) + 16 * wr + m + 14;                       \
        { const int _Pb = 0; PPAIR(rbg +  0) }                            \
        { const int _Pb = 1; PPAIR(rbg +  2) }                            \
        { const int _Pb = 2; PPAIR(rbg +  4) }                            \
        { const int _Pb = 3; PPAIR(rbg +  6) }                            \
        { const int _Pb = 4; PPAIR(rbg +  8) }                            \
        { const int _Pb = 5; PPAIR(rbg + 10) }                            \
        { const int _Pb = 6; PPAIR(rbg + 12) }                            \
        { const int _Pb = 7; PPAIR(rb7) }                                 \
        const int ocb = c0 + 64 * wc + m;                                 \
        const int or0 = r0 + (CBASE) + 16 * wr + g * 4;                   \
        { STORE_TILE(0, acc0) STORE_TILE(1, acc1)                         \
          STORE_TILE(2, acc2) STORE_TILE(3, acc3) }

    #define STORE_TILE(t, a) {                                            \
        const int _oc = ocb + (t) * 16;                                   \
        if (_oc < N_OUT) {                                                \
            _Pragma("unroll")                                             \
            for (int r = 0; r < 4; ++r) {                                 \
                if (or0 + r < N_OUT)                                      \
                    out[(or0 + r) * N_OUT + _oc] = a[r] + b0;             \
            }                                                             \
        }                                                                 \
    }

    // ---- chunk 0: compute rows [0,64); stage rows [78,142) underneath ----
    {
        float4 s0 = make_float4(0.f,0.f,0.f,0.f), s1 = s0, s2 = s0, s3 = s0, s4 = s0;
        ISSUE_ITEM(78, tid,        s0);
        ISSUE_ITEM(78, tid +  512, s1);
        ISSUE_ITEM(78, tid + 1024, s2);
        ISSUE_ITEM(78, tid + 1536, s3);
        if (tid < CITEMS - 2048) ISSUE_ITEM(78, tid + 2048, s4);   // 256 tail

        DO_CHUNK(0)

        COMMIT_ITEM(78, tid,        s0);
        COMMIT_ITEM(78, tid +  512, s1);
        COMMIT_ITEM(78, tid + 1024, s2);
        COMMIT_ITEM(78, tid + 1536, s3);
        if (tid < CITEMS - 2048) COMMIT_ITEM(78, tid + 2048, s4);
        __syncthreads();
    }
    // ---- chunk 1: compute rows [64,128) ----
    {
        DO_CHUNK(64)
    }
    #undef PPAIR
    #undef DO_CHUNK
    #undef STORE_TILE
}

extern "C" void kernel_launch(void* const* d_in, const int* in_sizes, int n_in,
                              void* d_out, int out_size, void* d_ws, size_t ws_size,
                              hipStream_t stream) {
    const float* x    = (const float*)d_in[0];
    const float* w    = (const float*)d_in[1];
    const float* bias = (const float*)d_in[2];
    float* out        = (float*)d_out;
    unsigned short* bt = (unsigned short*)d_ws;     // 16 KB B-table

    btab_fill_kernel<<<dim3(16), dim3(64), 0, stream>>>(w, bt);

    dim3 block(512);
    dim3 grid(32 * 32);   // 1024 blocks, swizzled in-kernel; up to 4/CU
    Conv2DScratch_82025285419642_kernel<<<grid, block, 0, stream>>>(
        x, bt, bias, out);
}